// Round 7
// baseline (5438.049 us; speedup 1.0000x reference)
//
#include <hip/hip_runtime.h>
#include <stdint.h>
#include <stddef.h>

// Persistent-LSTM, T=1024, B=64, E=H=512 (fp32 in/out).
//
// R8: single-barrier step + register-direct h fragments.
//  Post-mortems R5-R7: producer tail & MFMA chaining are not the period
//  setter; the ~5700cy/step of non-busy time is 3 barrier drains + the
//  poll gate + the Hl LDS round trip. R8 deletes 2 barriers and Hl:
//  (a) WS REGION RE-LAYOUT [16 kk][4 q][16 n][2 slot] qwords: lane (q,n)'s
//      MFMA A-fragment for k-slice kk = 2 adjacent qwords. Each wave polls
//      exactly the fragments it consumes, straight into registers (hreg[32],
//      sentinel-checked per-lane, bit-cast to bf16x8). No Hl LDS write, no
//      Hl barrier, no ds_read. 4x LLC poll traffic (64KB/block/step),
//      coalesced by the layout, overlapped with x-MFMAs.
//  (b) X DOUBLE-BUFFER => staging needs no barrier: iter t stages x_t into
//      Xbuf[(t+1)&1], x-MFMA reads Xbuf[t&1]. The single barrier sits
//      between act/exch-write and cell/publish. Cross-wave safety:
//      - exch: write(t) pre-barrier, read(t) post-barrier; write(t+1)
//        requires check(t+1) <= all publishes(t) <= all cell-reads(t).
//      - Xbuf: writer of iter t+1 passed barrier(t); reader of iter t is
//        pre-barrier(t). Disjoint buffers within an iter.
//      - poison drains at the barrier (vmcnt0); publish follows it.
//  Poll issue stays ~1000cy (staging) after step start = R4-equivalent
//  timing (R5 proved earlier sampling reads pre-publish state).
//
// Exchange protocol otherwise as R3..R7 (proven): mod-3 regions per group,
// 8B chunks, relaxed agent-scope atomics, fresh := != POISON8 && != INIT8;
// producer-side poison one region ahead after poll success; t==1 skips
// poll+h-MFMA (h_0=0); t==Tn skips publish. XCD-pair grouping.
// Numerics unchanged: weights bf16 hi+lo, x hi/lo split, h single bf16
// => absmax ~0.0039.

#define Tn 1024
#define Bn 64
#define Hn 512
#define En 512
#define NGROUP 4
#define NJBLK 32
#define NBLOCK (NGROUP * NJBLK)
#define POISON8 0x7F807F807F807F80ull
#define INIT8   0xAAAAAAAAAAAAAAAAull

using bf16x8 = __attribute__((ext_vector_type(8))) __bf16;
using f32x4  = __attribute__((ext_vector_type(4))) float;
using u16x8  = __attribute__((ext_vector_type(8))) unsigned short;
using u16x4  = __attribute__((ext_vector_type(4))) unsigned short;
using u64x2  = __attribute__((ext_vector_type(2))) unsigned long long;

__device__ __forceinline__ unsigned short f2bf(float f) {
    unsigned u = __builtin_bit_cast(unsigned, f);
    unsigned r = (u + 0x7FFFu + ((u >> 16) & 1u)) >> 16;
    return (unsigned short)r;
}
__device__ __forceinline__ float bf2f(unsigned short b) {
    unsigned u = ((unsigned)b) << 16;
    return __builtin_bit_cast(float, u);
}
// region chunk index for h column c (4 bf16 at col c..c+3), batch row b:
// layout [kk][q][n][slot]: kk=c>>5, q=(c>>3)&3, slot=(c>>2)&1
__device__ __forceinline__ int chunk_idx(int c, int b) {
    return ((c >> 5) << 7) + (((c >> 3) & 3) << 5) + (b << 1) + ((c >> 2) & 1);
}

__global__ __launch_bounds__(256, 1) void lstm_persistent(
    const float* __restrict__ embeds,
    const float* __restrict__ wx0, const float* __restrict__ wh0, const float* __restrict__ bs0,
    const float* __restrict__ wx1, const float* __restrict__ wh1, const float* __restrict__ bs1,
    const float* __restrict__ wx2, const float* __restrict__ wh2, const float* __restrict__ bs2,
    const float* __restrict__ wx3, const float* __restrict__ wh3, const float* __restrict__ bs3,
    float* __restrict__ out, void* __restrict__ ws)
{
    __shared__ unsigned short Xhi[2][16][520];   // x operand hi, dbuf, +8 pad
    __shared__ unsigned short Xlo[2][16][520];   // x operand lo
    __shared__ float exch[4][16][17];            // gate exchange g/i/f/o

    const int tid  = threadIdx.x;
    const int wav  = tid >> 6;     // wave = gate (0=g,1=i,2=f,3=o)
    const int lane = tid & 63;
    const int q    = lane >> 4;
    const int n    = lane & 15;

    // XCD-pair grouping: XCD = blockIdx%8 (round-robin dispatch).
    const int bidx = blockIdx.x;
    const int gid  = (bidx >> 1) & 3;
    const int kid  = ((bidx >> 3) << 1) | (bidx & 1);
    const int b0   = gid * 16;
    const int j0   = kid * 16;

    // ws: [NGROUP][3][2048] qwords; region r holds h_s for s%3==r.
    unsigned long long* gbase = (unsigned long long*)ws + (size_t)gid * 3 * 2048;

    const float* wxp = (wav == 0) ? wx0 : (wav == 1) ? wx1 : (wav == 2) ? wx2 : wx3;
    const float* whp = (wav == 0) ? wh0 : (wav == 1) ? wh1 : (wav == 2) ? wh2 : wh3;
    const float* bsp = (wav == 0) ? bs0 : (wav == 1) ? bs1 : (wav == 2) ? bs2 : bs3;

    // ---- preload weight fragments into registers (bf16 hi/lo) ----
    // B-frag layout for mfma_f32_16x16x32_bf16: lane holds B[k=q*8+i][n]
    bf16x8 WXhi[16], WXlo[16], WHhi[16], WHlo[16];
    const int col = j0 + n;
    #pragma unroll
    for (int kk = 0; kk < 16; ++kk) {
        u16x8 xh, xl, hh, hl;
        #pragma unroll
        for (int i = 0; i < 8; ++i) {
            int k = kk * 32 + q * 8 + i;
            float w  = wxp[(size_t)k * Hn + col];
            unsigned short hi = f2bf(w);
            xh[i] = hi;
            xl[i] = f2bf(w - bf2f(hi));
            w  = whp[(size_t)k * Hn + col];
            hi = f2bf(w);
            hh[i] = hi;
            hl[i] = f2bf(w - bf2f(hi));
        }
        WXhi[kk] = __builtin_bit_cast(bf16x8, xh);
        WXlo[kk] = __builtin_bit_cast(bf16x8, xl);
        WHhi[kk] = __builtin_bit_cast(bf16x8, hh);
        WHlo[kk] = __builtin_bit_cast(bf16x8, hl);
    }
    const float bias_l = bsp[col];
    float c_state = 0.f;   // thread owns (b,j) = (tid>>4, tid&15)
    const int b = tid >> 4, j = tid & 15;

    // ---- prologue: stage x_0 -> Xbuf[1]; prefetch x_1 into xpre ----
    float4 xpre[8];
    #pragma unroll
    for (int it = 0; it < 8; ++it) {
        int idx = tid + it * 256;
        int r = idx >> 7, cc = idx & 127;
        float4 v = ((const float4*)(embeds + ((size_t)(b0 + r)) * En))[cc];
        float fs[4] = {v.x, v.y, v.z, v.w};
        u16x4 vh, vl;
        #pragma unroll
        for (int e = 0; e < 4; ++e) {
            unsigned short hb = f2bf(fs[e]);
            vh[e] = hb;
            vl[e] = f2bf(fs[e] - bf2f(hb));
        }
        *(u16x4*)&Xhi[1][r][cc * 4] = vh;
        *(u16x4*)&Xlo[1][r][cc * 4] = vl;
    }
    #pragma unroll
    for (int it = 0; it < 8; ++it) {
        int idx = tid + it * 256;
        int r = idx >> 7, cc = idx & 127;
        xpre[it] = ((const float4*)(embeds + ((size_t)1 * Bn + b0 + r) * En))[cc];
    }
    __syncthreads();   // Xbuf[1] visible to all waves before iter-1 MFMA

    for (int t = 1; t <= Tn; ++t) {
        const int tau = t - 1;
        const int rbuf = t & 1;          // x-MFMA reads Xbuf[rbuf]
        const int wbuf = rbuf ^ 1;       // staging writes Xbuf[wbuf]

        // ---- stage x_t (in xpre) -> Xbuf[wbuf] for the NEXT iter ----
        if (t < Tn) {
            #pragma unroll
            for (int it = 0; it < 8; ++it) {
                int idx = tid + it * 256;
                int r = idx >> 7, cc = idx & 127;
                float4 v = xpre[it];
                float fs[4] = {v.x, v.y, v.z, v.w};
                u16x4 vh, vl;
                #pragma unroll
                for (int e = 0; e < 4; ++e) {
                    unsigned short hb = f2bf(fs[e]);
                    vh[e] = hb;
                    vl[e] = f2bf(fs[e] - bf2f(hb));
                }
                *(u16x4*)&Xhi[wbuf][r][cc * 4] = vh;
                *(u16x4*)&Xlo[wbuf][r][cc * 4] = vl;
            }
        }

        // ---- poll issue: per-lane fragment loads (region (t-1)%3) ----
        unsigned long long hreg[32];
        unsigned long long* src = gbase + (size_t)((t - 1) % 3) * 2048;
        const int fbase = q * 32 + n * 2;
        if (t > 1) {
            #pragma unroll
            for (int kk = 0; kk < 16; ++kk) {
                hreg[2 * kk]     = __hip_atomic_load(src + kk * 128 + fbase,
                                       __ATOMIC_RELAXED, __HIP_MEMORY_SCOPE_AGENT);
                hreg[2 * kk + 1] = __hip_atomic_load(src + kk * 128 + fbase + 1,
                                       __ATOMIC_RELAXED, __HIP_MEMORY_SCOPE_AGENT);
            }
        }

        // ---- prefetch x_{t+1} into xpre ----
        if (t + 1 < Tn) {
            #pragma unroll
            for (int it = 0; it < 8; ++it) {
                int idx = tid + it * 256;
                int r = idx >> 7, cc = idx & 127;
                xpre[it] = ((const float4*)(embeds + ((size_t)(t + 1) * Bn + b0 + r) * En))[cc];
            }
        }

        f32x4 acc, acc2, acc3, accH, accL;
        acc[0] = bias_l; acc[1] = bias_l; acc[2] = bias_l; acc[3] = bias_l;
        acc2[0] = 0.f; acc2[1] = 0.f; acc2[2] = 0.f; acc2[3] = 0.f;
        acc3[0] = 0.f; acc3[1] = 0.f; acc3[2] = 0.f; acc3[3] = 0.f;
        accH = acc2; accL = acc2;

        // ---- x part: 3 independent 16-deep MFMA chains ----
        #pragma unroll
        for (int kk = 0; kk < 16; ++kk) {
            bf16x8 ah = __builtin_bit_cast(bf16x8, *(const u16x8*)&Xhi[rbuf][n][kk * 32 + q * 8]);
            bf16x8 al = __builtin_bit_cast(bf16x8, *(const u16x8*)&Xlo[rbuf][n][kk * 32 + q * 8]);
            acc  = __builtin_amdgcn_mfma_f32_16x16x32_bf16(ah, WXhi[kk], acc, 0, 0, 0);
            acc2 = __builtin_amdgcn_mfma_f32_16x16x32_bf16(ah, WXlo[kk], acc2, 0, 0, 0);
            acc3 = __builtin_amdgcn_mfma_f32_16x16x32_bf16(al, WXhi[kk], acc3, 0, 0, 0);
        }

        if (t > 1) {
            // ---- per-lane poll check: re-load only still-unready chunks ----
            unsigned bad = 0;
            #pragma unroll
            for (int i = 0; i < 32; ++i)
                bad |= (hreg[i] == POISON8 || hreg[i] == INIT8) ? (1u << i) : 0u;
            while (bad) {
                #pragma unroll
                for (int i = 0; i < 32; ++i)
                    if (bad & (1u << i))
                        hreg[i] = __hip_atomic_load(src + (i >> 1) * 128 + fbase + (i & 1),
                                      __ATOMIC_RELAXED, __HIP_MEMORY_SCOPE_AGENT);
                unsigned nb = 0;
                #pragma unroll
                for (int i = 0; i < 32; ++i)
                    nb |= (hreg[i] == POISON8 || hreg[i] == INIT8) ? (1u << i) : 0u;
                bad = nb;
            }
        }

        // ---- poison own chunks of region (t+1)%3 (holds dead h_{t-2}).
        //      Safe: poll success above => peers' step-(t-1) reads done.
        //      Drained (vmcnt0) at the barrier below, before publish. ----
        if (tid < 64) {
            int pb = tid >> 2, pq = tid & 3;
            __hip_atomic_store(gbase + (size_t)((t + 1) % 3) * 2048
                                   + chunk_idx(j0 + pq * 4, pb),
                               (unsigned long long)POISON8,
                               __ATOMIC_RELAXED, __HIP_MEMORY_SCOPE_AGENT);
        }

        if (t > 1) {
            // ---- h part: fragments straight from registers ----
            #pragma unroll
            for (int kk = 0; kk < 16; ++kk) {
                u64x2 p;
                p[0] = hreg[2 * kk];
                p[1] = hreg[2 * kk + 1];
                bf16x8 a = __builtin_bit_cast(bf16x8, p);
                accH = __builtin_amdgcn_mfma_f32_16x16x32_bf16(a, WHhi[kk], accH, 0, 0, 0);
                accL = __builtin_amdgcn_mfma_f32_16x16x32_bf16(a, WHlo[kk], accL, 0, 0, 0);
            }
        }

        // ---- activations; D layout: row=(q*4+r)=batch, col=n=j ----
        #pragma unroll
        for (int r = 0; r < 4; ++r) {
            float zv  = acc[r] + acc2[r] + acc3[r] + accH[r] + accL[r];
            float arg = (wav == 0) ? -2.f * zv : -zv;
            float s   = __builtin_amdgcn_rcpf(1.f + __expf(arg));
            float act = (wav == 0) ? (2.f * s - 1.f) : s;
            exch[wav][q * 4 + r][n] = act;
        }

        __syncthreads();   // THE barrier: exch ready; poison drained

        // ---- per-thread cell update ----
        float hv;
        {
            float g  = exch[0][b][j];
            float ig = exch[1][b][j];
            float fg = exch[2][b][j];
            float og = exch[3][b][j];
            c_state = g * ig + c_state * fg;
            float e2 = __expf(-2.f * c_state);
            float th = 2.f * __builtin_amdgcn_rcpf(1.f + e2) - 1.f;
            hv = th * og;
        }

        // ---- shuffle-pack publish: lanes 4c..4c+3 hold (b, j=4c..4c+3) ----
        {
            unsigned pk = (unsigned)f2bf(hv);
            unsigned v1 = __shfl_down((int)pk, 1);
            unsigned v2 = __shfl_down((int)pk, 2);
            unsigned v3 = __shfl_down((int)pk, 3);
            if ((lane & 3) == 0 && t < Tn) {
                unsigned long long qv =
                    (unsigned long long)(pk | (v1 << 16))
                    | ((unsigned long long)(v2 | (v3 << 16)) << 32);
                __hip_atomic_store(gbase + (size_t)(t % 3) * 2048
                                       + chunk_idx(j0 + (j & ~3), b),
                                   qv, __ATOMIC_RELAXED, __HIP_MEMORY_SCOPE_AGENT);
            }
        }

        // ---- output store (fire-and-forget, after publish) ----
        out[((size_t)tau * Bn + b0 + b) * Hn + j0 + j] = hv;
    }
}

extern "C" void kernel_launch(void* const* d_in, const int* in_sizes, int n_in,
                              void* d_out, int out_size, void* d_ws, size_t ws_size,
                              hipStream_t stream) {
    // setup_inputs order: embeds, (w_gx,w_gh,bias_g), (w_ix,w_ih,bias_i),
    //                     (w_fx,w_fh,bias_f), (w_ox,w_oh,bias_o)
    lstm_persistent<<<dim3(NBLOCK), dim3(256), 0, stream>>>(
        (const float*)d_in[0],
        (const float*)d_in[1], (const float*)d_in[2], (const float*)d_in[3],
        (const float*)d_in[4], (const float*)d_in[5], (const float*)d_in[6],
        (const float*)d_in[7], (const float*)d_in[8], (const float*)d_in[9],
        (const float*)d_in[10], (const float*)d_in[11], (const float*)d_in[12],
        (float*)d_out, d_ws);
}